// Round 1
// baseline (1386.643 us; speedup 1.0000x reference)
//
#include <hip/hip_runtime.h>
#include <hip/hip_bf16.h>

#define N_NODES 50000
#define DIM 128
#define N_EDGES 800000

typedef __bf16 bf16_t;
typedef bf16_t bf16x4 __attribute__((ext_vector_type(4)));
typedef bf16_t bf16x8 __attribute__((ext_vector_type(8)));
typedef float f32x4 __attribute__((ext_vector_type(4)));

// ---------------- Kernel 1: LayerNorm -> h, acc = (1+eps)*h ----------------
// one wave (64 lanes) per row, 2 floats per lane
__global__ __launch_bounds__(256) void k_ln(
    const float* __restrict__ x, const float* __restrict__ gamma,
    const float* __restrict__ beta, const float* __restrict__ epsp,
    float* __restrict__ h, float* __restrict__ acc) {
  const int lane = threadIdx.x & 63;
  const int row  = blockIdx.x * 4 + (threadIdx.x >> 6);
  if (row >= N_NODES) return;
  const float2 v = *(const float2*)(x + (size_t)row * DIM + lane * 2);
  float s  = v.x + v.y;
  float ss = v.x * v.x + v.y * v.y;
#pragma unroll
  for (int d = 1; d < 64; d <<= 1) {
    s  += __shfl_xor(s, d);
    ss += __shfl_xor(ss, d);
  }
  const float mu   = s * (1.0f / 128.0f);
  const float var  = ss * (1.0f / 128.0f) - mu * mu;
  const float rstd = rsqrtf(var + 1e-5f);
  const float2 g = *(const float2*)(gamma + lane * 2);
  const float2 b = *(const float2*)(beta + lane * 2);
  const float h0 = (v.x - mu) * rstd * g.x + b.x;
  const float h1 = (v.y - mu) * rstd * g.y + b.y;
  const float epv = 1.0f + epsp[0];
  *(float2*)(h   + (size_t)row * DIM + lane * 2) = make_float2(h0, h1);
  *(float2*)(acc + (size_t)row * DIM + lane * 2) = make_float2(h0 * epv, h1 * epv);
}

// ---------------- Kernel 2: scatter-add acc[row] += h[col] ----------------
// 32 lanes per edge, one float4 (+4 fp32 atomics) per lane
__global__ __launch_bounds__(256) void k_scatter(
    const int* __restrict__ erows, const int* __restrict__ ecols,
    const float* __restrict__ h, float* __restrict__ acc) {
  const int gid = blockIdx.x * 256 + threadIdx.x;
  const int e = gid >> 5;
  if (e >= N_EDGES) return;
  const int chunk = (gid & 31) * 4;
  const int src = ecols[e];
  const int dst = erows[e];
  const float4 v = *(const float4*)(h + (size_t)src * DIM + chunk);
  float* p = acc + (size_t)dst * DIM + chunk;
  unsafeAtomicAdd(p + 0, v.x);
  unsafeAtomicAdd(p + 1, v.y);
  unsafeAtomicAdd(p + 2, v.z);
  unsafeAtomicAdd(p + 3, v.w);
}

// ---------------- Kernel 3: fused  silu(acc@W1^T+b1)@W2^T + b2 + x --------
// 256 threads (4 waves), 128 rows/block; W1,W2 in LDS (bf16, pad 136);
// 16x16x32 bf16 MFMA; intermediate redistributed through LDS.
__global__ __launch_bounds__(256) void k_mlp(
    const float* __restrict__ acc, const float* __restrict__ x,
    const float* __restrict__ W1, const float* __restrict__ b1,
    const float* __restrict__ W2, const float* __restrict__ b2,
    float* __restrict__ out) {
  __shared__ __attribute__((aligned(16))) bf16_t lsA[128 * 136]; // W1, then inter
  __shared__ __attribute__((aligned(16))) bf16_t lsB[128 * 136]; // W2

  const int tid  = threadIdx.x;
  const int lane = tid & 63;
  const int w    = tid >> 6;
  const int l15  = lane & 15;
  const int lq   = lane >> 4;

  // stage W1, W2 -> LDS as bf16
#pragma unroll
  for (int i = 0; i < 16; ++i) {
    const int idx = i * 1024 + tid * 4;
    const int r = idx >> 7, c = idx & 127;
    const float4 v1 = *(const float4*)(W1 + idx);
    const float4 v2 = *(const float4*)(W2 + idx);
    *(bf16x4*)&lsA[r * 136 + c] =
        (bf16x4){(bf16_t)v1.x, (bf16_t)v1.y, (bf16_t)v1.z, (bf16_t)v1.w};
    *(bf16x4*)&lsB[r * 136 + c] =
        (bf16x4){(bf16_t)v2.x, (bf16_t)v2.y, (bf16_t)v2.z, (bf16_t)v2.w};
  }

  const int rb = blockIdx.x * 128 + w * 32;

  // A fragments for GEMM1 straight from global (fp32 -> bf16)
  bf16x8 af[2][4];
#pragma unroll
  for (int t = 0; t < 2; ++t)
#pragma unroll
    for (int ks = 0; ks < 4; ++ks) {
      int row = rb + t * 16 + l15;
      row = row < N_NODES ? row : N_NODES - 1;
      const float* p = acc + (size_t)row * DIM + ks * 32 + lq * 8;
      const float4 u0 = *(const float4*)p;
      const float4 u1 = *(const float4*)(p + 4);
      af[t][ks] = (bf16x8){(bf16_t)u0.x, (bf16_t)u0.y, (bf16_t)u0.z, (bf16_t)u0.w,
                           (bf16_t)u1.x, (bf16_t)u1.y, (bf16_t)u1.z, (bf16_t)u1.w};
    }
  __syncthreads();

  // GEMM1: c1 = acc @ W1^T
  f32x4 c1[2][8] = {};
#pragma unroll
  for (int cb = 0; cb < 8; ++cb)
#pragma unroll
    for (int ks = 0; ks < 4; ++ks) {
      const bf16x8 bf = *(const bf16x8*)&lsA[(cb * 16 + l15) * 136 + ks * 32 + lq * 8];
      c1[0][cb] = __builtin_amdgcn_mfma_f32_16x16x32_bf16(af[0][ks], bf, c1[0][cb], 0, 0, 0);
      c1[1][cb] = __builtin_amdgcn_mfma_f32_16x16x32_bf16(af[1][ks], bf, c1[1][cb], 0, 0, 0);
    }
  __syncthreads(); // all waves done reading W1 region

  // bias + SiLU, write intermediate (bf16) into lsA in row-major [128][136]
#pragma unroll
  for (int cb = 0; cb < 8; ++cb) {
    const float b1v = b1[cb * 16 + l15];
#pragma unroll
    for (int t = 0; t < 2; ++t)
#pragma unroll
      for (int r = 0; r < 4; ++r) {
        float v = c1[t][cb][r] + b1v;
        v = v / (1.0f + __expf(-v));
        const int ri = w * 32 + t * 16 + lq * 4 + r;
        lsA[ri * 136 + cb * 16 + l15] = (bf16_t)v;
      }
  }
  __syncthreads();

  // A fragments for GEMM2 from LDS intermediate
  bf16x8 a2[2][4];
#pragma unroll
  for (int t = 0; t < 2; ++t)
#pragma unroll
    for (int ks = 0; ks < 4; ++ks)
      a2[t][ks] = *(const bf16x8*)&lsA[(w * 32 + t * 16 + l15) * 136 + ks * 32 + lq * 8];

  // GEMM2: c2 = inter @ W2^T
  f32x4 c2[2][8] = {};
#pragma unroll
  for (int cb = 0; cb < 8; ++cb)
#pragma unroll
    for (int ks = 0; ks < 4; ++ks) {
      const bf16x8 bf = *(const bf16x8*)&lsB[(cb * 16 + l15) * 136 + ks * 32 + lq * 8];
      c2[0][cb] = __builtin_amdgcn_mfma_f32_16x16x32_bf16(a2[0][ks], bf, c2[0][cb], 0, 0, 0);
      c2[1][cb] = __builtin_amdgcn_mfma_f32_16x16x32_bf16(a2[1][ks], bf, c2[1][cb], 0, 0, 0);
    }

  // epilogue: out = x + c2 + b2
#pragma unroll
  for (int cb = 0; cb < 8; ++cb) {
    const int c = cb * 16 + l15;
    const float b2v = b2[c];
#pragma unroll
    for (int t = 0; t < 2; ++t)
#pragma unroll
      for (int r = 0; r < 4; ++r) {
        const int row = rb + t * 16 + lq * 4 + r;
        if (row < N_NODES)
          out[(size_t)row * DIM + c] = x[(size_t)row * DIM + c] + c2[t][cb][r] + b2v;
      }
  }
}

extern "C" void kernel_launch(void* const* d_in, const int* in_sizes, int n_in,
                              void* d_out, int out_size, void* d_ws, size_t ws_size,
                              hipStream_t stream) {
  const float* x     = (const float*)d_in[0];
  const int*   erows = (const int*)d_in[1];
  const int*   ecols = (const int*)d_in[2];
  const float* W1    = (const float*)d_in[3];
  const float* b1    = (const float*)d_in[4];
  const float* W2    = (const float*)d_in[5];
  const float* b2    = (const float*)d_in[6];
  const float* gamma = (const float*)d_in[7];
  const float* beta  = (const float*)d_in[8];
  const float* eps   = (const float*)d_in[9];
  float* out = (float*)d_out;

  float* h   = (float*)d_ws;                      // N*D fp32
  float* acc = h + (size_t)N_NODES * DIM;         // N*D fp32

  k_ln<<<N_NODES / 4, 256, 0, stream>>>(x, gamma, beta, eps, h, acc);
  k_scatter<<<(N_EDGES * 32) / 256, 256, 0, stream>>>(erows, ecols, h, acc);
  k_mlp<<<(N_NODES + 127) / 128, 256, 0, stream>>>(acc, x, W1, b1, W2, b2, out);
}

// Round 2
// 192.077 us; speedup vs baseline: 7.2192x; 7.2192x over previous
//
#include <hip/hip_runtime.h>
#include <hip/hip_bf16.h>

#define N_NODES 50000
#define DIM 128
#define N_EDGES 800000
#define SCAN_BLOCKS 196   // ceil(50000/256)

typedef __bf16 bf16_t;
typedef bf16_t bf16x2 __attribute__((ext_vector_type(2)));
typedef bf16_t bf16x4 __attribute__((ext_vector_type(4)));
typedef bf16_t bf16x8 __attribute__((ext_vector_type(8)));
typedef float f32x4 __attribute__((ext_vector_type(4)));

// ---------------- Kernel 1: LayerNorm -> h (bf16); also zero deg ----------
__global__ __launch_bounds__(256) void k_ln(
    const float* __restrict__ x, const float* __restrict__ gamma,
    const float* __restrict__ beta, bf16_t* __restrict__ h,
    int* __restrict__ deg) {
  const int gid = blockIdx.x * 256 + threadIdx.x;
  if (gid < SCAN_BLOCKS * 256) deg[gid] = 0;
  const int lane = threadIdx.x & 63;
  const int row  = blockIdx.x * 4 + (threadIdx.x >> 6);
  const float2 v = *(const float2*)(x + (size_t)row * DIM + lane * 2);
  float s  = v.x + v.y;
  float ss = v.x * v.x + v.y * v.y;
#pragma unroll
  for (int d = 1; d < 64; d <<= 1) {
    s  += __shfl_xor(s, d);
    ss += __shfl_xor(ss, d);
  }
  const float mu   = s * (1.0f / 128.0f);
  const float var  = ss * (1.0f / 128.0f) - mu * mu;
  const float rstd = rsqrtf(var + 1e-5f);
  const float2 g = *(const float2*)(gamma + lane * 2);
  const float2 b = *(const float2*)(beta + lane * 2);
  const float h0 = (v.x - mu) * rstd * g.x + b.x;
  const float h1 = (v.y - mu) * rstd * g.y + b.y;
  *(bf16x2*)(h + (size_t)row * DIM + lane * 2) = (bf16x2){(bf16_t)h0, (bf16_t)h1};
}

// ---------------- Kernel 2: histogram of dst degrees ----------------------
__global__ __launch_bounds__(256) void k_hist(
    const int* __restrict__ erows, int* __restrict__ deg) {
  const int e = blockIdx.x * 256 + threadIdx.x;
  if (e < N_EDGES) atomicAdd(&deg[erows[e]], 1);
}

// ---------------- Kernel 3a: per-block exclusive scan ---------------------
__global__ __launch_bounds__(256) void k_scan1(
    const int* __restrict__ deg, int* __restrict__ lscan,
    int* __restrict__ partials) {
  const int t = threadIdx.x, lane = t & 63, w = t >> 6;
  const int idx = blockIdx.x * 256 + t;
  const int val = (idx < N_NODES) ? deg[idx] : 0;
  int v = val;
#pragma unroll
  for (int d = 1; d < 64; d <<= 1) {
    const int n = __shfl_up(v, d);
    if (lane >= d) v += n;
  }
  __shared__ int wsum[4];
  if (lane == 63) wsum[w] = v;
  __syncthreads();
  int woff = 0;
  for (int k = 0; k < w; ++k) woff += wsum[k];
  const int incl = v + woff;
  lscan[idx] = incl - val;
  if (t == 255) partials[blockIdx.x] = incl;
}

// ---------------- Kernel 3b: scan of block partials -----------------------
__global__ __launch_bounds__(256) void k_scan2(
    const int* __restrict__ partials, int* __restrict__ blockoff) {
  const int t = threadIdx.x, lane = t & 63, w = t >> 6;
  const int val = (t < SCAN_BLOCKS) ? partials[t] : 0;
  int v = val;
#pragma unroll
  for (int d = 1; d < 64; d <<= 1) {
    const int n = __shfl_up(v, d);
    if (lane >= d) v += n;
  }
  __shared__ int wsum[4];
  if (lane == 63) wsum[w] = v;
  __syncthreads();
  int woff = 0;
  for (int k = 0; k < w; ++k) woff += wsum[k];
  blockoff[t] = v + woff - val;
}

// ---------------- Kernel 3c: finalize starts + cursors --------------------
__global__ __launch_bounds__(256) void k_final(
    const int* __restrict__ lscan, const int* __restrict__ blockoff,
    int* __restrict__ starts, int* __restrict__ cursor) {
  const int idx = blockIdx.x * 256 + threadIdx.x;
  if (idx < N_NODES) {
    const int s = lscan[idx] + blockoff[idx >> 8];
    starts[idx] = s;
    cursor[idx] = s;
  } else if (idx == N_NODES) {
    starts[N_NODES] = N_EDGES;
  }
}

// ---------------- Kernel 4: reorder edge sources by dst -------------------
__global__ __launch_bounds__(256) void k_reorder(
    const int* __restrict__ erows, const int* __restrict__ ecols,
    int* __restrict__ cursor, int* __restrict__ sorted_src) {
  const int e = blockIdx.x * 256 + threadIdx.x;
  if (e >= N_EDGES) return;
  const int pos = atomicAdd(&cursor[erows[e]], 1);
  sorted_src[pos] = ecols[e];
}

// ---------------- Kernel 5: gather-sum: acc = (1+eps)*h + sum h[src] ------
// one wave per node; lane owns 2 columns (packed bf16x2 as uint)
__global__ __launch_bounds__(256) void k_gather(
    const unsigned int* __restrict__ h2, const int* __restrict__ starts,
    const int* __restrict__ sorted_src, const float* __restrict__ epsp,
    bf16_t* __restrict__ acc) {
  const int lane = threadIdx.x & 63;
  const int node = blockIdx.x * 4 + (threadIdx.x >> 6);
  const int s = starts[node], e = starts[node + 1];
  const unsigned int hv = h2[(size_t)node * 64 + lane];
  const float epv = 1.0f + epsp[0];
  float ax = __uint_as_float(hv << 16) * epv;
  float ay = __uint_as_float(hv & 0xffff0000u) * epv;
  for (int base = s; base < e; base += 64) {
    const int cnt = min(64, e - base);
    const int myidx = (base + lane < e) ? sorted_src[base + lane] : 0;
    for (int j = 0; j < cnt; ++j) {
      const int src = __shfl(myidx, j);
      const unsigned int v = h2[(size_t)src * 64 + lane];
      ax += __uint_as_float(v << 16);
      ay += __uint_as_float(v & 0xffff0000u);
    }
  }
  *(bf16x2*)(acc + (size_t)node * DIM + lane * 2) = (bf16x2){(bf16_t)ax, (bf16_t)ay};
}

// ---------------- Kernel 6: fused  silu(acc@W1^T+b1)@W2^T + b2 + x --------
__global__ __launch_bounds__(256) void k_mlp(
    const bf16_t* __restrict__ acc, const float* __restrict__ x,
    const float* __restrict__ W1, const float* __restrict__ b1,
    const float* __restrict__ W2, const float* __restrict__ b2,
    float* __restrict__ out) {
  __shared__ __attribute__((aligned(16))) bf16_t lsA[128 * 136]; // W1, then inter
  __shared__ __attribute__((aligned(16))) bf16_t lsB[128 * 136]; // W2

  const int tid  = threadIdx.x;
  const int lane = tid & 63;
  const int w    = tid >> 6;
  const int l15  = lane & 15;
  const int lq   = lane >> 4;

  // stage W1, W2 -> LDS as bf16
#pragma unroll
  for (int i = 0; i < 16; ++i) {
    const int idx = i * 1024 + tid * 4;
    const int r = idx >> 7, c = idx & 127;
    const float4 v1 = *(const float4*)(W1 + idx);
    const float4 v2 = *(const float4*)(W2 + idx);
    *(bf16x4*)&lsA[r * 136 + c] =
        (bf16x4){(bf16_t)v1.x, (bf16_t)v1.y, (bf16_t)v1.z, (bf16_t)v1.w};
    *(bf16x4*)&lsB[r * 136 + c] =
        (bf16x4){(bf16_t)v2.x, (bf16_t)v2.y, (bf16_t)v2.z, (bf16_t)v2.w};
  }

  const int rb = blockIdx.x * 128 + w * 32;

  // A fragments for GEMM1 straight from global (bf16)
  bf16x8 af[2][4];
#pragma unroll
  for (int t = 0; t < 2; ++t)
#pragma unroll
    for (int ks = 0; ks < 4; ++ks) {
      int row = rb + t * 16 + l15;
      row = row < N_NODES ? row : N_NODES - 1;
      af[t][ks] = *(const bf16x8*)(acc + (size_t)row * DIM + ks * 32 + lq * 8);
    }
  __syncthreads();

  // GEMM1: c1 = acc @ W1^T
  f32x4 c1[2][8] = {};
#pragma unroll
  for (int cb = 0; cb < 8; ++cb)
#pragma unroll
    for (int ks = 0; ks < 4; ++ks) {
      const bf16x8 bf = *(const bf16x8*)&lsA[(cb * 16 + l15) * 136 + ks * 32 + lq * 8];
      c1[0][cb] = __builtin_amdgcn_mfma_f32_16x16x32_bf16(af[0][ks], bf, c1[0][cb], 0, 0, 0);
      c1[1][cb] = __builtin_amdgcn_mfma_f32_16x16x32_bf16(af[1][ks], bf, c1[1][cb], 0, 0, 0);
    }
  __syncthreads(); // all waves done reading W1 region

  // bias + SiLU, write intermediate (bf16) into lsA in row-major [128][136]
#pragma unroll
  for (int cb = 0; cb < 8; ++cb) {
    const float b1v = b1[cb * 16 + l15];
#pragma unroll
    for (int t = 0; t < 2; ++t)
#pragma unroll
      for (int r = 0; r < 4; ++r) {
        float v = c1[t][cb][r] + b1v;
        v = v / (1.0f + __expf(-v));
        const int ri = w * 32 + t * 16 + lq * 4 + r;
        lsA[ri * 136 + cb * 16 + l15] = (bf16_t)v;
      }
  }
  __syncthreads();

  // A fragments for GEMM2 from LDS intermediate
  bf16x8 a2[2][4];
#pragma unroll
  for (int t = 0; t < 2; ++t)
#pragma unroll
    for (int ks = 0; ks < 4; ++ks)
      a2[t][ks] = *(const bf16x8*)&lsA[(w * 32 + t * 16 + l15) * 136 + ks * 32 + lq * 8];

  // GEMM2: c2 = inter @ W2^T
  f32x4 c2[2][8] = {};
#pragma unroll
  for (int cb = 0; cb < 8; ++cb)
#pragma unroll
    for (int ks = 0; ks < 4; ++ks) {
      const bf16x8 bf = *(const bf16x8*)&lsB[(cb * 16 + l15) * 136 + ks * 32 + lq * 8];
      c2[0][cb] = __builtin_amdgcn_mfma_f32_16x16x32_bf16(a2[0][ks], bf, c2[0][cb], 0, 0, 0);
      c2[1][cb] = __builtin_amdgcn_mfma_f32_16x16x32_bf16(a2[1][ks], bf, c2[1][cb], 0, 0, 0);
    }

  // epilogue: out = x + c2 + b2
#pragma unroll
  for (int cb = 0; cb < 8; ++cb) {
    const int c = cb * 16 + l15;
    const float b2v = b2[c];
#pragma unroll
    for (int t = 0; t < 2; ++t)
#pragma unroll
      for (int r = 0; r < 4; ++r) {
        const int row = rb + t * 16 + lq * 4 + r;
        if (row < N_NODES)
          out[(size_t)row * DIM + c] = x[(size_t)row * DIM + c] + c2[t][cb][r] + b2v;
      }
  }
}

extern "C" void kernel_launch(void* const* d_in, const int* in_sizes, int n_in,
                              void* d_out, int out_size, void* d_ws, size_t ws_size,
                              hipStream_t stream) {
  const float* x     = (const float*)d_in[0];
  const int*   erows = (const int*)d_in[1];
  const int*   ecols = (const int*)d_in[2];
  const float* W1    = (const float*)d_in[3];
  const float* b1    = (const float*)d_in[4];
  const float* W2    = (const float*)d_in[5];
  const float* b2    = (const float*)d_in[6];
  const float* gamma = (const float*)d_in[7];
  const float* beta  = (const float*)d_in[8];
  const float* eps   = (const float*)d_in[9];
  float* out = (float*)d_out;

  char* ws = (char*)d_ws;
  bf16_t* h        = (bf16_t*)(ws);                  // 12,800,000 B
  bf16_t* acc      = (bf16_t*)(ws + 12800000);       // 12,800,000 B
  int*    sorted   = (int*)(ws + 25600000);          //  3,200,000 B
  int*    deg      = (int*)(ws + 28800000);          //    200,704 B
  int*    lscan    = (int*)(ws + 29000704);          //    200,704 B
  int*    starts   = (int*)(ws + 29201408);          //    200,016 B
  int*    cursor   = (int*)(ws + 29401424);          //    200,000 B
  int*    partials = (int*)(ws + 29601424);          //      1,024 B
  int*    blockoff = (int*)(ws + 29602448);          //      1,024 B

  k_ln     <<<N_NODES / 4, 256, 0, stream>>>(x, gamma, beta, h, deg);
  k_hist   <<<(N_EDGES + 255) / 256, 256, 0, stream>>>(erows, deg);
  k_scan1  <<<SCAN_BLOCKS, 256, 0, stream>>>(deg, lscan, partials);
  k_scan2  <<<1, 256, 0, stream>>>(partials, blockoff);
  k_final  <<<SCAN_BLOCKS + 1, 256, 0, stream>>>(lscan, blockoff, starts, cursor);
  k_reorder<<<(N_EDGES + 255) / 256, 256, 0, stream>>>(erows, ecols, cursor, sorted);
  k_gather <<<N_NODES / 4, 256, 0, stream>>>((const unsigned int*)h, starts, sorted, eps, acc);
  k_mlp    <<<(N_NODES + 127) / 128, 256, 0, stream>>>(acc, x, W1, b1, W2, b2, out);
}

// Round 3
// 166.746 us; speedup vs baseline: 8.3159x; 1.1519x over previous
//
#include <hip/hip_runtime.h>
#include <hip/hip_bf16.h>

#define N_NODES 50000
#define DIM 128
#define N_EDGES 800000
#define SCAN_BLOCKS 196   // ceil(50000/256)

typedef __bf16 bf16_t;
typedef bf16_t bf16x2 __attribute__((ext_vector_type(2)));
typedef bf16_t bf16x4 __attribute__((ext_vector_type(4)));
typedef bf16_t bf16x8 __attribute__((ext_vector_type(8)));
typedef float f32x4 __attribute__((ext_vector_type(4)));

__device__ __forceinline__ float bf_lo(unsigned int u) {
  return __uint_as_float(u << 16);
}
__device__ __forceinline__ float bf_hi(unsigned int u) {
  return __uint_as_float(u & 0xffff0000u);
}

// ------- Kernel 1: LayerNorm -> h (bf16), fused degree histogram ----------
__global__ __launch_bounds__(256) void k_lnhist(
    const float* __restrict__ x, const float* __restrict__ gamma,
    const float* __restrict__ beta, const int* __restrict__ erows,
    bf16_t* __restrict__ h, int* __restrict__ deg) {
  const int gid = blockIdx.x * 256 + threadIdx.x;
  const int lane = threadIdx.x & 63;
  const int row  = blockIdx.x * 4 + (threadIdx.x >> 6);
  const float2 v = *(const float2*)(x + (size_t)row * DIM + lane * 2);
  float s  = v.x + v.y;
  float ss = v.x * v.x + v.y * v.y;
#pragma unroll
  for (int d = 1; d < 64; d <<= 1) {
    s  += __shfl_xor(s, d);
    ss += __shfl_xor(ss, d);
  }
  const float mu   = s * (1.0f / 128.0f);
  const float var  = ss * (1.0f / 128.0f) - mu * mu;
  const float rstd = rsqrtf(var + 1e-5f);
  const float2 g = *(const float2*)(gamma + lane * 2);
  const float2 b = *(const float2*)(beta + lane * 2);
  const float h0 = (v.x - mu) * rstd * g.x + b.x;
  const float h1 = (v.y - mu) * rstd * g.y + b.y;
  *(bf16x2*)(h + (size_t)row * DIM + lane * 2) = (bf16x2){(bf16_t)h0, (bf16_t)h1};
  if (gid < N_EDGES) atomicAdd(&deg[erows[gid]], 1);
}

// ---------------- Kernel 2a: per-block exclusive scan ---------------------
__global__ __launch_bounds__(256) void k_scan1(
    const int* __restrict__ deg, int* __restrict__ lscan,
    int* __restrict__ partials) {
  const int t = threadIdx.x, lane = t & 63, w = t >> 6;
  const int idx = blockIdx.x * 256 + t;
  const int val = (idx < N_NODES) ? deg[idx] : 0;
  int v = val;
#pragma unroll
  for (int d = 1; d < 64; d <<= 1) {
    const int n = __shfl_up(v, d);
    if (lane >= d) v += n;
  }
  __shared__ int wsum[4];
  if (lane == 63) wsum[w] = v;
  __syncthreads();
  int woff = 0;
  for (int k = 0; k < w; ++k) woff += wsum[k];
  const int incl = v + woff;
  lscan[idx] = incl - val;
  if (t == 255) partials[blockIdx.x] = incl;
}

// ---------------- Kernel 2b: scan of block partials -----------------------
__global__ __launch_bounds__(256) void k_scan2(
    const int* __restrict__ partials, int* __restrict__ blockoff) {
  const int t = threadIdx.x, lane = t & 63, w = t >> 6;
  const int val = (t < SCAN_BLOCKS) ? partials[t] : 0;
  int v = val;
#pragma unroll
  for (int d = 1; d < 64; d <<= 1) {
    const int n = __shfl_up(v, d);
    if (lane >= d) v += n;
  }
  __shared__ int wsum[4];
  if (lane == 63) wsum[w] = v;
  __syncthreads();
  int woff = 0;
  for (int k = 0; k < w; ++k) woff += wsum[k];
  blockoff[t] = v + woff - val;
}

// ---------------- Kernel 2c: finalize starts + cursors --------------------
__global__ __launch_bounds__(256) void k_final(
    const int* __restrict__ lscan, const int* __restrict__ blockoff,
    int* __restrict__ starts, int* __restrict__ cursor) {
  const int idx = blockIdx.x * 256 + threadIdx.x;
  if (idx < N_NODES) {
    const int s = lscan[idx] + blockoff[idx >> 8];
    starts[idx] = s;
    cursor[idx] = s;
  } else if (idx == N_NODES) {
    starts[N_NODES] = N_EDGES;
  }
}

// ---------------- Kernel 3: reorder edge sources by dst -------------------
__global__ __launch_bounds__(256) void k_reorder(
    const int* __restrict__ erows, const int* __restrict__ ecols,
    int* __restrict__ cursor, int* __restrict__ sorted_src) {
  const int e = blockIdx.x * 256 + threadIdx.x;
  if (e >= N_EDGES) return;
  const int pos = atomicAdd(&cursor[erows[e]], 1);
  sorted_src[pos] = ecols[e];
}

// ---------------- Kernel 4: gather-sum: acc = (1+eps)*h + sum h[src] ------
// one wave per node; half-wave owns a full 128-col row (8B/lane);
// 2 edges per half per iteration -> 4 independent loads in flight.
__global__ __launch_bounds__(256) void k_gather(
    const uint2* __restrict__ h4, const int* __restrict__ starts,
    const int* __restrict__ sorted_src, const float* __restrict__ epsp,
    bf16_t* __restrict__ acc) {
  const int tid  = threadIdx.x;
  const int lane = tid & 63;
  const int half = lane >> 5;
  const int l31  = lane & 31;
  const int node = blockIdx.x * 4 + (tid >> 6);
  const int s = starts[node], e = starts[node + 1];
  f32x4 a0 = {0.f, 0.f, 0.f, 0.f};
  f32x4 a1 = {0.f, 0.f, 0.f, 0.f};
  for (int base = s; base < e; base += 64) {
    const int cnt = e - base;
    const int m = cnt < 64 ? cnt : 64;
    const int myidx = (lane < m) ? sorted_src[base + lane] : 0;
    for (int j = 0; j < m; j += 4) {
      const int o0 = j + half;
      const int o1 = j + 2 + half;
      const int s0 = __shfl(myidx, o0);
      const int s1 = __shfl(myidx, o1);
      uint2 v0 = h4[(size_t)s0 * 32 + l31];
      uint2 v1 = h4[(size_t)s1 * 32 + l31];
      if (o0 >= m) { v0.x = 0u; v0.y = 0u; }
      if (o1 >= m) { v1.x = 0u; v1.y = 0u; }
      a0[0] += bf_lo(v0.x); a0[1] += bf_hi(v0.x);
      a0[2] += bf_lo(v0.y); a0[3] += bf_hi(v0.y);
      a1[0] += bf_lo(v1.x); a1[1] += bf_hi(v1.x);
      a1[2] += bf_lo(v1.y); a1[3] += bf_hi(v1.y);
    }
  }
  f32x4 t = a0 + a1;
#pragma unroll
  for (int k = 0; k < 4; ++k) t[k] += __shfl_xor(t[k], 32);
  if (half == 0) {
    const uint2 hv = h4[(size_t)node * 32 + l31];
    const float epv = 1.0f + epsp[0];
    t[0] += bf_lo(hv.x) * epv; t[1] += bf_hi(hv.x) * epv;
    t[2] += bf_lo(hv.y) * epv; t[3] += bf_hi(hv.y) * epv;
    *(bf16x4*)(acc + (size_t)node * DIM + l31 * 4) =
        (bf16x4){(bf16_t)t[0], (bf16_t)t[1], (bf16_t)t[2], (bf16_t)t[3]};
  }
}

// ---------------- Kernel 5: fused  silu(acc@W1^T+b1)@W2^T + b2 + x --------
__global__ __launch_bounds__(256) void k_mlp(
    const bf16_t* __restrict__ acc, const float* __restrict__ x,
    const float* __restrict__ W1, const float* __restrict__ b1,
    const float* __restrict__ W2, const float* __restrict__ b2,
    float* __restrict__ out) {
  __shared__ __attribute__((aligned(16))) bf16_t lsA[128 * 136]; // W1, then inter
  __shared__ __attribute__((aligned(16))) bf16_t lsB[128 * 136]; // W2

  const int tid  = threadIdx.x;
  const int lane = tid & 63;
  const int w    = tid >> 6;
  const int l15  = lane & 15;
  const int lq   = lane >> 4;

  // stage W1, W2 -> LDS as bf16
#pragma unroll
  for (int i = 0; i < 16; ++i) {
    const int idx = i * 1024 + tid * 4;
    const int r = idx >> 7, c = idx & 127;
    const float4 v1 = *(const float4*)(W1 + idx);
    const float4 v2 = *(const float4*)(W2 + idx);
    *(bf16x4*)&lsA[r * 136 + c] =
        (bf16x4){(bf16_t)v1.x, (bf16_t)v1.y, (bf16_t)v1.z, (bf16_t)v1.w};
    *(bf16x4*)&lsB[r * 136 + c] =
        (bf16x4){(bf16_t)v2.x, (bf16_t)v2.y, (bf16_t)v2.z, (bf16_t)v2.w};
  }

  const int rb = blockIdx.x * 128 + w * 32;

  // A fragments for GEMM1 straight from global (bf16)
  bf16x8 af[2][4];
#pragma unroll
  for (int t = 0; t < 2; ++t)
#pragma unroll
    for (int ks = 0; ks < 4; ++ks) {
      int row = rb + t * 16 + l15;
      row = row < N_NODES ? row : N_NODES - 1;
      af[t][ks] = *(const bf16x8*)(acc + (size_t)row * DIM + ks * 32 + lq * 8);
    }
  __syncthreads();

  // GEMM1: c1 = acc @ W1^T
  f32x4 c1[2][8] = {};
#pragma unroll
  for (int cb = 0; cb < 8; ++cb)
#pragma unroll
    for (int ks = 0; ks < 4; ++ks) {
      const bf16x8 bf = *(const bf16x8*)&lsA[(cb * 16 + l15) * 136 + ks * 32 + lq * 8];
      c1[0][cb] = __builtin_amdgcn_mfma_f32_16x16x32_bf16(af[0][ks], bf, c1[0][cb], 0, 0, 0);
      c1[1][cb] = __builtin_amdgcn_mfma_f32_16x16x32_bf16(af[1][ks], bf, c1[1][cb], 0, 0, 0);
    }
  __syncthreads(); // all waves done reading W1 region

  // bias + SiLU, write intermediate (bf16) into lsA in row-major [128][136]
#pragma unroll
  for (int cb = 0; cb < 8; ++cb) {
    const float b1v = b1[cb * 16 + l15];
#pragma unroll
    for (int t = 0; t < 2; ++t)
#pragma unroll
      for (int r = 0; r < 4; ++r) {
        float v = c1[t][cb][r] + b1v;
        v = v / (1.0f + __expf(-v));
        const int ri = w * 32 + t * 16 + lq * 4 + r;
        lsA[ri * 136 + cb * 16 + l15] = (bf16_t)v;
      }
  }
  __syncthreads();

  // A fragments for GEMM2 from LDS intermediate
  bf16x8 a2[2][4];
#pragma unroll
  for (int t = 0; t < 2; ++t)
#pragma unroll
    for (int ks = 0; ks < 4; ++ks)
      a2[t][ks] = *(const bf16x8*)&lsA[(w * 32 + t * 16 + l15) * 136 + ks * 32 + lq * 8];

  // GEMM2: c2 = inter @ W2^T
  f32x4 c2[2][8] = {};
#pragma unroll
  for (int cb = 0; cb < 8; ++cb)
#pragma unroll
    for (int ks = 0; ks < 4; ++ks) {
      const bf16x8 bf = *(const bf16x8*)&lsB[(cb * 16 + l15) * 136 + ks * 32 + lq * 8];
      c2[0][cb] = __builtin_amdgcn_mfma_f32_16x16x32_bf16(a2[0][ks], bf, c2[0][cb], 0, 0, 0);
      c2[1][cb] = __builtin_amdgcn_mfma_f32_16x16x32_bf16(a2[1][ks], bf, c2[1][cb], 0, 0, 0);
    }

  // epilogue: out = x + c2 + b2
#pragma unroll
  for (int cb = 0; cb < 8; ++cb) {
    const int c = cb * 16 + l15;
    const float b2v = b2[c];
#pragma unroll
    for (int t = 0; t < 2; ++t)
#pragma unroll
      for (int r = 0; r < 4; ++r) {
        const int row = rb + t * 16 + lq * 4 + r;
        if (row < N_NODES)
          out[(size_t)row * DIM + c] = x[(size_t)row * DIM + c] + c2[t][cb][r] + b2v;
      }
  }
}

extern "C" void kernel_launch(void* const* d_in, const int* in_sizes, int n_in,
                              void* d_out, int out_size, void* d_ws, size_t ws_size,
                              hipStream_t stream) {
  const float* x     = (const float*)d_in[0];
  const int*   erows = (const int*)d_in[1];
  const int*   ecols = (const int*)d_in[2];
  const float* W1    = (const float*)d_in[3];
  const float* b1    = (const float*)d_in[4];
  const float* W2    = (const float*)d_in[5];
  const float* b2    = (const float*)d_in[6];
  const float* gamma = (const float*)d_in[7];
  const float* beta  = (const float*)d_in[8];
  const float* eps   = (const float*)d_in[9];
  float* out = (float*)d_out;

  char* ws = (char*)d_ws;
  bf16_t* h        = (bf16_t*)(ws);                  // 12,800,000 B
  bf16_t* acc      = (bf16_t*)(ws + 12800000);       // 12,800,000 B
  int*    sorted   = (int*)(ws + 25600000);          //  3,200,000 B
  int*    deg      = (int*)(ws + 28800000);          //    200,704 B
  int*    lscan    = (int*)(ws + 29000704);          //    200,704 B
  int*    starts   = (int*)(ws + 29201408);          //    200,016 B
  int*    cursor   = (int*)(ws + 29401424);          //    200,000 B
  int*    partials = (int*)(ws + 29601424);          //      1,024 B
  int*    blockoff = (int*)(ws + 29602448);          //      1,024 B

  hipMemsetAsync(deg, 0, SCAN_BLOCKS * 256 * sizeof(int), stream);
  k_lnhist <<<N_NODES / 4, 256, 0, stream>>>(x, gamma, beta, erows, h, deg);
  k_scan1  <<<SCAN_BLOCKS, 256, 0, stream>>>(deg, lscan, partials);
  k_scan2  <<<1, 256, 0, stream>>>(partials, blockoff);
  k_final  <<<SCAN_BLOCKS + 1, 256, 0, stream>>>(lscan, blockoff, starts, cursor);
  k_reorder<<<(N_EDGES + 255) / 256, 256, 0, stream>>>(erows, ecols, cursor, sorted);
  k_gather <<<N_NODES / 4, 256, 0, stream>>>((const uint2*)h, starts, sorted, eps, acc);
  k_mlp    <<<(N_NODES + 127) / 128, 256, 0, stream>>>(acc, x, W1, b1, W2, b2, out);
}

// Round 4
// 143.378 us; speedup vs baseline: 9.6712x; 1.1630x over previous
//
#include <hip/hip_runtime.h>
#include <hip/hip_bf16.h>

#define N_NODES 50000
#define DIM 128
#define N_EDGES 800000
#define SCAN_BLOCKS 196   // ceil(50000/256)
#define NBUCKETS 196      // ceil(50000/256) nodes>>8 buckets
#define BINA_EPB 4096     // edges per k_binA block

typedef __bf16 bf16_t;
typedef bf16_t bf16x2 __attribute__((ext_vector_type(2)));
typedef bf16_t bf16x4 __attribute__((ext_vector_type(4)));
typedef bf16_t bf16x8 __attribute__((ext_vector_type(8)));
typedef float f32x4 __attribute__((ext_vector_type(4)));

__device__ __forceinline__ float bf_lo(unsigned int u) {
  return __uint_as_float(u << 16);
}
__device__ __forceinline__ float bf_hi(unsigned int u) {
  return __uint_as_float(u & 0xffff0000u);
}

// ------- Kernel 1: LayerNorm -> h (bf16), fused degree histogram ----------
__global__ __launch_bounds__(256) void k_lnhist(
    const float* __restrict__ x, const float* __restrict__ gamma,
    const float* __restrict__ beta, const int* __restrict__ erows,
    bf16_t* __restrict__ h, int* __restrict__ deg) {
  const int gid = blockIdx.x * 256 + threadIdx.x;
  const int lane = threadIdx.x & 63;
  const int row  = blockIdx.x * 4 + (threadIdx.x >> 6);
  const float2 v = *(const float2*)(x + (size_t)row * DIM + lane * 2);
  float s  = v.x + v.y;
  float ss = v.x * v.x + v.y * v.y;
#pragma unroll
  for (int d = 1; d < 64; d <<= 1) {
    s  += __shfl_xor(s, d);
    ss += __shfl_xor(ss, d);
  }
  const float mu   = s * (1.0f / 128.0f);
  const float var  = ss * (1.0f / 128.0f) - mu * mu;
  const float rstd = rsqrtf(var + 1e-5f);
  const float2 g = *(const float2*)(gamma + lane * 2);
  const float2 b = *(const float2*)(beta + lane * 2);
  const float h0 = (v.x - mu) * rstd * g.x + b.x;
  const float h1 = (v.y - mu) * rstd * g.y + b.y;
  *(bf16x2*)(h + (size_t)row * DIM + lane * 2) = (bf16x2){(bf16_t)h0, (bf16_t)h1};
  if (gid < N_EDGES) atomicAdd(&deg[erows[gid]], 1);
}

// ---------------- Kernel 2a: per-block exclusive scan ---------------------
__global__ __launch_bounds__(256) void k_scan1(
    const int* __restrict__ deg, int* __restrict__ lscan,
    int* __restrict__ partials) {
  const int t = threadIdx.x, lane = t & 63, w = t >> 6;
  const int idx = blockIdx.x * 256 + t;
  const int val = (idx < N_NODES) ? deg[idx] : 0;
  int v = val;
#pragma unroll
  for (int d = 1; d < 64; d <<= 1) {
    const int n = __shfl_up(v, d);
    if (lane >= d) v += n;
  }
  __shared__ int wsum[4];
  if (lane == 63) wsum[w] = v;
  __syncthreads();
  int woff = 0;
  for (int k = 0; k < w; ++k) woff += wsum[k];
  const int incl = v + woff;
  lscan[idx] = incl - val;
  if (t == 255) partials[blockIdx.x] = incl;
}

// ---------------- Kernel 2b: scan of block partials -----------------------
__global__ __launch_bounds__(256) void k_scan2(
    const int* __restrict__ partials, int* __restrict__ blockoff) {
  const int t = threadIdx.x, lane = t & 63, w = t >> 6;
  const int val = (t < SCAN_BLOCKS) ? partials[t] : 0;
  int v = val;
#pragma unroll
  for (int d = 1; d < 64; d <<= 1) {
    const int n = __shfl_up(v, d);
    if (lane >= d) v += n;
  }
  __shared__ int wsum[4];
  if (lane == 63) wsum[w] = v;
  __syncthreads();
  int woff = 0;
  for (int k = 0; k < w; ++k) woff += wsum[k];
  blockoff[t] = v + woff - val;
}

// ---------------- Kernel 2c: finalize starts + bucket cursors -------------
__global__ __launch_bounds__(256) void k_final(
    const int* __restrict__ lscan, const int* __restrict__ blockoff,
    int* __restrict__ starts, int* __restrict__ bcursor) {
  const int idx = blockIdx.x * 256 + threadIdx.x;
  if (idx < N_NODES) {
    const int s = lscan[idx] + blockoff[idx >> 8];
    starts[idx] = s;
    if ((idx & 255) == 0) bcursor[idx >> 8] = s;
  } else if (idx == N_NODES) {
    starts[N_NODES] = N_EDGES;
  }
}

// ---------------- Kernel 3a: coarse bucket binning ------------------------
// 196 blocks x 4096 edges; LDS histogram over 196 buckets (dst>>8);
// one global atomic per (block,bucket) claims a contiguous range.
__global__ __launch_bounds__(256) void k_binA(
    const int* __restrict__ erows, const int* __restrict__ ecols,
    int* __restrict__ bcursor, unsigned int* __restrict__ tmp) {
  __shared__ int hist[256];
  const int t = threadIdx.x;
  const int base = blockIdx.x * BINA_EPB;
  hist[t] = 0;
  __syncthreads();
  int bkt[16];
  unsigned int pk[16];
#pragma unroll
  for (int i = 0; i < 16; ++i) {
    const int e = base + i * 256 + t;
    if (e < N_EDGES) {
      const int d = erows[e];
      const int c = ecols[e];
      bkt[i] = d >> 8;
      pk[i] = ((unsigned int)(d & 255) << 16) | (unsigned int)c;
      atomicAdd(&hist[bkt[i]], 1);
    } else {
      bkt[i] = -1;
    }
  }
  __syncthreads();
  const int cnt = hist[t];
  int g = 0;
  if (t < NBUCKETS && cnt > 0) g = atomicAdd(&bcursor[t], cnt);
  __syncthreads();
  hist[t] = g;  // reuse as local write cursor
  __syncthreads();
#pragma unroll
  for (int i = 0; i < 16; ++i) {
    if (bkt[i] >= 0) {
      const int pos = atomicAdd(&hist[bkt[i]], 1);
      tmp[pos] = pk[i];
    }
  }
}

// ---------------- Kernel 3b: within-bucket exact placement ----------------
// one block per bucket; per-node cursors in LDS; writes land in the
// bucket's contiguous ~16KB slice of sorted -> no write amplification.
__global__ __launch_bounds__(256) void k_binB(
    const unsigned int* __restrict__ tmp, const int* __restrict__ starts,
    int* __restrict__ sorted) {
  __shared__ int cur[256];
  const int b = blockIdx.x, t = threadIdx.x;
  const int nodebase = b * 256;
  const int nidx = nodebase + t;
  cur[t] = (nidx < N_NODES) ? starts[nidx] : N_EDGES;
  __syncthreads();
  const int rs = starts[nodebase];
  const int re = (nodebase + 256 <= N_NODES) ? starts[nodebase + 256] : N_EDGES;
  for (int e = rs + t; e < re; e += 256) {
    const unsigned int v = tmp[e];
    const int pos = atomicAdd(&cur[v >> 16], 1);
    sorted[pos] = (int)(v & 0xffffu);
  }
}

// ---------------- Kernel 4: gather-sum: acc = (1+eps)*h + sum h[src] ------
__global__ __launch_bounds__(256) void k_gather(
    const uint2* __restrict__ h4, const int* __restrict__ starts,
    const int* __restrict__ sorted_src, const float* __restrict__ epsp,
    bf16_t* __restrict__ acc) {
  const int tid  = threadIdx.x;
  const int lane = tid & 63;
  const int half = lane >> 5;
  const int l31  = lane & 31;
  const int node = blockIdx.x * 4 + (tid >> 6);
  const int s = starts[node], e = starts[node + 1];
  f32x4 a0 = {0.f, 0.f, 0.f, 0.f};
  f32x4 a1 = {0.f, 0.f, 0.f, 0.f};
  for (int base = s; base < e; base += 64) {
    const int cnt = e - base;
    const int m = cnt < 64 ? cnt : 64;
    const int myidx = (lane < m) ? sorted_src[base + lane] : 0;
    for (int j = 0; j < m; j += 4) {
      const int o0 = j + half;
      const int o1 = j + 2 + half;
      const int s0 = __shfl(myidx, o0);
      const int s1 = __shfl(myidx, o1);
      uint2 v0 = h4[(size_t)s0 * 32 + l31];
      uint2 v1 = h4[(size_t)s1 * 32 + l31];
      if (o0 >= m) { v0.x = 0u; v0.y = 0u; }
      if (o1 >= m) { v1.x = 0u; v1.y = 0u; }
      a0[0] += bf_lo(v0.x); a0[1] += bf_hi(v0.x);
      a0[2] += bf_lo(v0.y); a0[3] += bf_hi(v0.y);
      a1[0] += bf_lo(v1.x); a1[1] += bf_hi(v1.x);
      a1[2] += bf_lo(v1.y); a1[3] += bf_hi(v1.y);
    }
  }
  f32x4 t = a0 + a1;
#pragma unroll
  for (int k = 0; k < 4; ++k) t[k] += __shfl_xor(t[k], 32);
  if (half == 0) {
    const uint2 hv = h4[(size_t)node * 32 + l31];
    const float epv = 1.0f + epsp[0];
    t[0] += bf_lo(hv.x) * epv; t[1] += bf_hi(hv.x) * epv;
    t[2] += bf_lo(hv.y) * epv; t[3] += bf_hi(hv.y) * epv;
    *(bf16x4*)(acc + (size_t)node * DIM + l31 * 4) =
        (bf16x4){(bf16_t)t[0], (bf16_t)t[1], (bf16_t)t[2], (bf16_t)t[3]};
  }
}

// ---------------- Kernel 5: fused  silu(acc@W1^T+b1)@W2^T + b2 + x --------
__global__ __launch_bounds__(256) void k_mlp(
    const bf16_t* __restrict__ acc, const float* __restrict__ x,
    const float* __restrict__ W1, const float* __restrict__ b1,
    const float* __restrict__ W2, const float* __restrict__ b2,
    float* __restrict__ out) {
  __shared__ __attribute__((aligned(16))) bf16_t lsA[128 * 136]; // W1, then inter
  __shared__ __attribute__((aligned(16))) bf16_t lsB[128 * 136]; // W2

  const int tid  = threadIdx.x;
  const int lane = tid & 63;
  const int w    = tid >> 6;
  const int l15  = lane & 15;
  const int lq   = lane >> 4;

  // stage W1, W2 -> LDS as bf16
#pragma unroll
  for (int i = 0; i < 16; ++i) {
    const int idx = i * 1024 + tid * 4;
    const int r = idx >> 7, c = idx & 127;
    const float4 v1 = *(const float4*)(W1 + idx);
    const float4 v2 = *(const float4*)(W2 + idx);
    *(bf16x4*)&lsA[r * 136 + c] =
        (bf16x4){(bf16_t)v1.x, (bf16_t)v1.y, (bf16_t)v1.z, (bf16_t)v1.w};
    *(bf16x4*)&lsB[r * 136 + c] =
        (bf16x4){(bf16_t)v2.x, (bf16_t)v2.y, (bf16_t)v2.z, (bf16_t)v2.w};
  }

  const int rb = blockIdx.x * 128 + w * 32;

  // A fragments for GEMM1 straight from global (bf16)
  bf16x8 af[2][4];
#pragma unroll
  for (int t = 0; t < 2; ++t)
#pragma unroll
    for (int ks = 0; ks < 4; ++ks) {
      int row = rb + t * 16 + l15;
      row = row < N_NODES ? row : N_NODES - 1;
      af[t][ks] = *(const bf16x8*)(acc + (size_t)row * DIM + ks * 32 + lq * 8);
    }
  __syncthreads();

  // GEMM1: c1 = acc @ W1^T
  f32x4 c1[2][8] = {};
#pragma unroll
  for (int cb = 0; cb < 8; ++cb)
#pragma unroll
    for (int ks = 0; ks < 4; ++ks) {
      const bf16x8 bf = *(const bf16x8*)&lsA[(cb * 16 + l15) * 136 + ks * 32 + lq * 8];
      c1[0][cb] = __builtin_amdgcn_mfma_f32_16x16x32_bf16(af[0][ks], bf, c1[0][cb], 0, 0, 0);
      c1[1][cb] = __builtin_amdgcn_mfma_f32_16x16x32_bf16(af[1][ks], bf, c1[1][cb], 0, 0, 0);
    }
  __syncthreads(); // all waves done reading W1 region

  // bias + SiLU, write intermediate (bf16) into lsA in row-major [128][136]
#pragma unroll
  for (int cb = 0; cb < 8; ++cb) {
    const float b1v = b1[cb * 16 + l15];
#pragma unroll
    for (int t = 0; t < 2; ++t)
#pragma unroll
      for (int r = 0; r < 4; ++r) {
        float v = c1[t][cb][r] + b1v;
        v = v / (1.0f + __expf(-v));
        const int ri = w * 32 + t * 16 + lq * 4 + r;
        lsA[ri * 136 + cb * 16 + l15] = (bf16_t)v;
      }
  }
  __syncthreads();

  // A fragments for GEMM2 from LDS intermediate
  bf16x8 a2[2][4];
#pragma unroll
  for (int t = 0; t < 2; ++t)
#pragma unroll
    for (int ks = 0; ks < 4; ++ks)
      a2[t][ks] = *(const bf16x8*)&lsA[(w * 32 + t * 16 + l15) * 136 + ks * 32 + lq * 8];

  // GEMM2: c2 = inter @ W2^T
  f32x4 c2[2][8] = {};
#pragma unroll
  for (int cb = 0; cb < 8; ++cb)
#pragma unroll
    for (int ks = 0; ks < 4; ++ks) {
      const bf16x8 bf = *(const bf16x8*)&lsB[(cb * 16 + l15) * 136 + ks * 32 + lq * 8];
      c2[0][cb] = __builtin_amdgcn_mfma_f32_16x16x32_bf16(a2[0][ks], bf, c2[0][cb], 0, 0, 0);
      c2[1][cb] = __builtin_amdgcn_mfma_f32_16x16x32_bf16(a2[1][ks], bf, c2[1][cb], 0, 0, 0);
    }

  // epilogue: out = x + c2 + b2
#pragma unroll
  for (int cb = 0; cb < 8; ++cb) {
    const int c = cb * 16 + l15;
    const float b2v = b2[c];
#pragma unroll
    for (int t = 0; t < 2; ++t)
#pragma unroll
      for (int r = 0; r < 4; ++r) {
        const int row = rb + t * 16 + lq * 4 + r;
        if (row < N_NODES)
          out[(size_t)row * DIM + c] = x[(size_t)row * DIM + c] + c2[t][cb][r] + b2v;
      }
  }
}

extern "C" void kernel_launch(void* const* d_in, const int* in_sizes, int n_in,
                              void* d_out, int out_size, void* d_ws, size_t ws_size,
                              hipStream_t stream) {
  const float* x     = (const float*)d_in[0];
  const int*   erows = (const int*)d_in[1];
  const int*   ecols = (const int*)d_in[2];
  const float* W1    = (const float*)d_in[3];
  const float* b1    = (const float*)d_in[4];
  const float* W2    = (const float*)d_in[5];
  const float* b2    = (const float*)d_in[6];
  const float* gamma = (const float*)d_in[7];
  const float* beta  = (const float*)d_in[8];
  const float* eps   = (const float*)d_in[9];
  float* out = (float*)d_out;

  char* ws = (char*)d_ws;
  bf16_t* h        = (bf16_t*)(ws);                  // 12,800,000 B
  bf16_t* acc      = (bf16_t*)(ws + 12800000);       // 12,800,000 B
  unsigned int* tmp = (unsigned int*)(ws + 12800000); // overlays acc (dead until gather)
  int*    sorted   = (int*)(ws + 25600000);          //  3,200,000 B
  int*    deg      = (int*)(ws + 28800000);          //    200,704 B
  int*    lscan    = (int*)(ws + 29000704);          //    200,704 B
  int*    starts   = (int*)(ws + 29201408);          //    200,016 B
  int*    partials = (int*)(ws + 29401424);          //      1,024 B
  int*    blockoff = (int*)(ws + 29402448);          //      1,024 B
  int*    bcursor  = (int*)(ws + 29403472);          //      1,024 B

  hipMemsetAsync(deg, 0, SCAN_BLOCKS * 256 * sizeof(int), stream);
  k_lnhist <<<N_NODES / 4, 256, 0, stream>>>(x, gamma, beta, erows, h, deg);
  k_scan1  <<<SCAN_BLOCKS, 256, 0, stream>>>(deg, lscan, partials);
  k_scan2  <<<1, 256, 0, stream>>>(partials, blockoff);
  k_final  <<<SCAN_BLOCKS + 1, 256, 0, stream>>>(lscan, blockoff, starts, bcursor);
  k_binA   <<<(N_EDGES + BINA_EPB - 1) / BINA_EPB, 256, 0, stream>>>(erows, ecols, bcursor, tmp);
  k_binB   <<<NBUCKETS, 256, 0, stream>>>(tmp, starts, sorted);
  k_gather <<<N_NODES / 4, 256, 0, stream>>>((const uint2*)h, starts, sorted, eps, acc);
  k_mlp    <<<(N_NODES + 127) / 128, 256, 0, stream>>>(acc, x, W1, b1, W2, b2, out);
}

// Round 5
// 116.675 us; speedup vs baseline: 11.8846x; 1.2289x over previous
//
#include <hip/hip_runtime.h>
#include <hip/hip_bf16.h>

#define N_NODES 50000
#define DIM 128
#define N_EDGES 800000
#define NBUCKETS 196      // ceil(50000/256) nodes>>8 buckets
#define BINA_EPB 4096     // edges per binning block

typedef __bf16 bf16_t;
typedef bf16_t bf16x2 __attribute__((ext_vector_type(2)));
typedef bf16_t bf16x4 __attribute__((ext_vector_type(4)));
typedef bf16_t bf16x8 __attribute__((ext_vector_type(8)));
typedef float f32x4 __attribute__((ext_vector_type(4)));

__device__ __forceinline__ float bf_lo(unsigned int u) {
  return __uint_as_float(u << 16);
}
__device__ __forceinline__ float bf_hi(unsigned int u) {
  return __uint_as_float(u & 0xffff0000u);
}

// ---------------- Kernel 1: LayerNorm -> h (bf16) -------------------------
__global__ __launch_bounds__(256) void k_ln(
    const float* __restrict__ x, const float* __restrict__ gamma,
    const float* __restrict__ beta, bf16_t* __restrict__ h) {
  const int lane = threadIdx.x & 63;
  const int row  = blockIdx.x * 4 + (threadIdx.x >> 6);
  const float2 v = *(const float2*)(x + (size_t)row * DIM + lane * 2);
  float s  = v.x + v.y;
  float ss = v.x * v.x + v.y * v.y;
#pragma unroll
  for (int d = 1; d < 64; d <<= 1) {
    s  += __shfl_xor(s, d);
    ss += __shfl_xor(ss, d);
  }
  const float mu   = s * (1.0f / 128.0f);
  const float var  = ss * (1.0f / 128.0f) - mu * mu;
  const float rstd = rsqrtf(var + 1e-5f);
  const float2 g = *(const float2*)(gamma + lane * 2);
  const float2 b = *(const float2*)(beta + lane * 2);
  const float h0 = (v.x - mu) * rstd * g.x + b.x;
  const float h1 = (v.y - mu) * rstd * g.y + b.y;
  *(bf16x2*)(h + (size_t)row * DIM + lane * 2) = (bf16x2){(bf16_t)h0, (bf16_t)h1};
}

// ---------------- Kernel 2: bucket histogram (LDS-aggregated) -------------
__global__ __launch_bounds__(256) void k_bhist(
    const int* __restrict__ erows, int* __restrict__ bhist) {
  __shared__ int hist[256];
  const int t = threadIdx.x;
  hist[t] = 0;
  __syncthreads();
  const int base = blockIdx.x * BINA_EPB;
#pragma unroll
  for (int i = 0; i < 16; ++i) {
    const int e = base + i * 256 + t;
    if (e < N_EDGES) atomicAdd(&hist[erows[e] >> 8], 1);
  }
  __syncthreads();
  if (t < NBUCKETS && hist[t] > 0) atomicAdd(&bhist[t], hist[t]);
}

// ---------------- Kernel 3: scan of 196 bucket counts ---------------------
__global__ __launch_bounds__(256) void k_bscan(
    const int* __restrict__ bhist, int* __restrict__ bstart,
    int* __restrict__ bcursor, int* __restrict__ starts) {
  const int t = threadIdx.x, lane = t & 63, w = t >> 6;
  const int val = (t < NBUCKETS) ? bhist[t] : 0;
  int v = val;
#pragma unroll
  for (int d = 1; d < 64; d <<= 1) {
    const int n = __shfl_up(v, d);
    if (lane >= d) v += n;
  }
  __shared__ int wsum[4];
  if (lane == 63) wsum[w] = v;
  __syncthreads();
  int woff = 0;
  for (int k = 0; k < w; ++k) woff += wsum[k];
  const int excl = v + woff - val;
  if (t < NBUCKETS) { bstart[t] = excl; bcursor[t] = excl; }
  if (t == NBUCKETS - 1) bstart[NBUCKETS] = excl + val;
  if (t == 0) starts[N_NODES] = N_EDGES;
}

// ---------------- Kernel 4: coarse bucket binning -------------------------
// LDS histogram over 196 buckets (dst>>8); one global atomic per
// (block,bucket) claims a contiguous range; packed (localdst,col) to tmp.
__global__ __launch_bounds__(256) void k_binA(
    const int* __restrict__ erows, const int* __restrict__ ecols,
    int* __restrict__ bcursor, unsigned int* __restrict__ tmp) {
  __shared__ int hist[256];
  const int t = threadIdx.x;
  const int base = blockIdx.x * BINA_EPB;
  hist[t] = 0;
  __syncthreads();
  int bkt[16];
  unsigned int pk[16];
#pragma unroll
  for (int i = 0; i < 16; ++i) {
    const int e = base + i * 256 + t;
    if (e < N_EDGES) {
      const int d = erows[e];
      const int c = ecols[e];
      bkt[i] = d >> 8;
      pk[i] = ((unsigned int)(d & 255) << 16) | (unsigned int)c;
      atomicAdd(&hist[bkt[i]], 1);
    } else {
      bkt[i] = -1;
    }
  }
  __syncthreads();
  const int cnt = hist[t];
  int g = 0;
  if (t < NBUCKETS && cnt > 0) g = atomicAdd(&bcursor[t], cnt);
  __syncthreads();
  hist[t] = g;  // reuse as local write cursor
  __syncthreads();
#pragma unroll
  for (int i = 0; i < 16; ++i) {
    if (bkt[i] >= 0) {
      const int pos = atomicAdd(&hist[bkt[i]], 1);
      tmp[pos] = pk[i];
    }
  }
}

// ---------------- Kernel 5: within-bucket placement + per-node starts -----
// one block per bucket; computes local node histogram + block scan ->
// per-node starts; then places edges into the bucket's contiguous slice.
__global__ __launch_bounds__(256) void k_binB(
    const unsigned int* __restrict__ tmp, const int* __restrict__ bstart,
    int* __restrict__ starts, int* __restrict__ sorted) {
  __shared__ int cnt[256];
  __shared__ int cur[256];
  __shared__ int wsum[4];
  const int b = blockIdx.x, t = threadIdx.x;
  const int rs = bstart[b], re = bstart[b + 1];
  cnt[t] = 0;
  __syncthreads();
  for (int e = rs + t; e < re; e += 256)
    atomicAdd(&cnt[tmp[e] >> 16], 1);
  __syncthreads();
  const int val = cnt[t];
  const int lane = t & 63, w = t >> 6;
  int v = val;
#pragma unroll
  for (int d = 1; d < 64; d <<= 1) {
    const int n = __shfl_up(v, d);
    if (lane >= d) v += n;
  }
  if (lane == 63) wsum[w] = v;
  __syncthreads();
  int woff = 0;
  for (int k = 0; k < w; ++k) woff += wsum[k];
  const int st = rs + v + woff - val;  // exclusive local scan + bucket base
  const int nidx = b * 256 + t;
  if (nidx < N_NODES) starts[nidx] = st;
  cur[t] = st;
  __syncthreads();
  for (int e = rs + t; e < re; e += 256) {
    const unsigned int pv = tmp[e];
    const int pos = atomicAdd(&cur[pv >> 16], 1);
    sorted[pos] = (int)(pv & 0xffffu);
  }
}

// ---------------- Kernel 6: gather-sum: acc = (1+eps)*h + sum h[src] ------
// one wave per node; half-wave owns the full 128-col row (8B/lane);
// 4 edges per half per iteration -> 8 independent loads in flight.
__global__ __launch_bounds__(256) void k_gather(
    const uint2* __restrict__ h4, const int* __restrict__ starts,
    const int* __restrict__ sorted_src, const float* __restrict__ epsp,
    bf16_t* __restrict__ acc) {
  const int tid  = threadIdx.x;
  const int lane = tid & 63;
  const int half = lane >> 5;
  const int l31  = lane & 31;
  const int node = blockIdx.x * 4 + (tid >> 6);
  const int s = starts[node], e = starts[node + 1];
  f32x4 a0 = {0.f, 0.f, 0.f, 0.f};
  f32x4 a1 = {0.f, 0.f, 0.f, 0.f};
  f32x4 a2 = {0.f, 0.f, 0.f, 0.f};
  f32x4 a3 = {0.f, 0.f, 0.f, 0.f};
  for (int base = s; base < e; base += 64) {
    const int cnt = e - base;
    const int m = cnt < 64 ? cnt : 64;
    const int myidx = (lane < m) ? sorted_src[base + lane] : 0;
    for (int j = 0; j < m; j += 8) {
      const int o0 = j + half;
      const int o1 = j + 2 + half;
      const int o2 = j + 4 + half;
      const int o3 = j + 6 + half;
      const int s0 = __shfl(myidx, o0);
      const int s1 = __shfl(myidx, o1);
      const int s2 = __shfl(myidx, o2);
      const int s3 = __shfl(myidx, o3);
      uint2 v0 = h4[(size_t)s0 * 32 + l31];
      uint2 v1 = h4[(size_t)s1 * 32 + l31];
      uint2 v2 = h4[(size_t)s2 * 32 + l31];
      uint2 v3 = h4[(size_t)s3 * 32 + l31];
      if (o0 >= m) { v0.x = 0u; v0.y = 0u; }
      if (o1 >= m) { v1.x = 0u; v1.y = 0u; }
      if (o2 >= m) { v2.x = 0u; v2.y = 0u; }
      if (o3 >= m) { v3.x = 0u; v3.y = 0u; }
      a0[0] += bf_lo(v0.x); a0[1] += bf_hi(v0.x);
      a0[2] += bf_lo(v0.y); a0[3] += bf_hi(v0.y);
      a1[0] += bf_lo(v1.x); a1[1] += bf_hi(v1.x);
      a1[2] += bf_lo(v1.y); a1[3] += bf_hi(v1.y);
      a2[0] += bf_lo(v2.x); a2[1] += bf_hi(v2.x);
      a2[2] += bf_lo(v2.y); a2[3] += bf_hi(v2.y);
      a3[0] += bf_lo(v3.x); a3[1] += bf_hi(v3.x);
      a3[2] += bf_lo(v3.y); a3[3] += bf_hi(v3.y);
    }
  }
  f32x4 t = (a0 + a1) + (a2 + a3);
#pragma unroll
  for (int k = 0; k < 4; ++k) t[k] += __shfl_xor(t[k], 32);
  if (half == 0) {
    const uint2 hv = h4[(size_t)node * 32 + l31];
    const float epv = 1.0f + epsp[0];
    t[0] += bf_lo(hv.x) * epv; t[1] += bf_hi(hv.x) * epv;
    t[2] += bf_lo(hv.y) * epv; t[3] += bf_hi(hv.y) * epv;
    *(bf16x4*)(acc + (size_t)node * DIM + l31 * 4) =
        (bf16x4){(bf16_t)t[0], (bf16_t)t[1], (bf16_t)t[2], (bf16_t)t[3]};
  }
}

// ---------------- Kernel 7: fused  silu(acc@W1^T+b1)@W2^T + b2 + x --------
__global__ __launch_bounds__(256) void k_mlp(
    const bf16_t* __restrict__ acc, const float* __restrict__ x,
    const float* __restrict__ W1, const float* __restrict__ b1,
    const float* __restrict__ W2, const float* __restrict__ b2,
    float* __restrict__ out) {
  __shared__ __attribute__((aligned(16))) bf16_t lsA[128 * 136]; // W1, then inter
  __shared__ __attribute__((aligned(16))) bf16_t lsB[128 * 136]; // W2

  const int tid  = threadIdx.x;
  const int lane = tid & 63;
  const int w    = tid >> 6;
  const int l15  = lane & 15;
  const int lq   = lane >> 4;

  // stage W1, W2 -> LDS as bf16
#pragma unroll
  for (int i = 0; i < 16; ++i) {
    const int idx = i * 1024 + tid * 4;
    const int r = idx >> 7, c = idx & 127;
    const float4 v1 = *(const float4*)(W1 + idx);
    const float4 v2 = *(const float4*)(W2 + idx);
    *(bf16x4*)&lsA[r * 136 + c] =
        (bf16x4){(bf16_t)v1.x, (bf16_t)v1.y, (bf16_t)v1.z, (bf16_t)v1.w};
    *(bf16x4*)&lsB[r * 136 + c] =
        (bf16x4){(bf16_t)v2.x, (bf16_t)v2.y, (bf16_t)v2.z, (bf16_t)v2.w};
  }

  const int rb = blockIdx.x * 128 + w * 32;

  // A fragments for GEMM1 straight from global (bf16)
  bf16x8 af[2][4];
#pragma unroll
  for (int t = 0; t < 2; ++t)
#pragma unroll
    for (int ks = 0; ks < 4; ++ks) {
      int row = rb + t * 16 + l15;
      row = row < N_NODES ? row : N_NODES - 1;
      af[t][ks] = *(const bf16x8*)(acc + (size_t)row * DIM + ks * 32 + lq * 8);
    }
  __syncthreads();

  // GEMM1: c1 = acc @ W1^T
  f32x4 c1[2][8] = {};
#pragma unroll
  for (int cb = 0; cb < 8; ++cb)
#pragma unroll
    for (int ks = 0; ks < 4; ++ks) {
      const bf16x8 bf = *(const bf16x8*)&lsA[(cb * 16 + l15) * 136 + ks * 32 + lq * 8];
      c1[0][cb] = __builtin_amdgcn_mfma_f32_16x16x32_bf16(af[0][ks], bf, c1[0][cb], 0, 0, 0);
      c1[1][cb] = __builtin_amdgcn_mfma_f32_16x16x32_bf16(af[1][ks], bf, c1[1][cb], 0, 0, 0);
    }
  __syncthreads(); // all waves done reading W1 region

  // bias + SiLU, write intermediate (bf16) into lsA in row-major [128][136]
#pragma unroll
  for (int cb = 0; cb < 8; ++cb) {
    const float b1v = b1[cb * 16 + l15];
#pragma unroll
    for (int t = 0; t < 2; ++t)
#pragma unroll
      for (int r = 0; r < 4; ++r) {
        float v = c1[t][cb][r] + b1v;
        v = v / (1.0f + __expf(-v));
        const int ri = w * 32 + t * 16 + lq * 4 + r;
        lsA[ri * 136 + cb * 16 + l15] = (bf16_t)v;
      }
  }
  __syncthreads();

  // A fragments for GEMM2 from LDS intermediate
  bf16x8 a2[2][4];
#pragma unroll
  for (int t = 0; t < 2; ++t)
#pragma unroll
    for (int ks = 0; ks < 4; ++ks)
      a2[t][ks] = *(const bf16x8*)&lsA[(w * 32 + t * 16 + l15) * 136 + ks * 32 + lq * 8];

  // GEMM2: c2 = inter @ W2^T
  f32x4 c2[2][8] = {};
#pragma unroll
  for (int cb = 0; cb < 8; ++cb)
#pragma unroll
    for (int ks = 0; ks < 4; ++ks) {
      const bf16x8 bf = *(const bf16x8*)&lsB[(cb * 16 + l15) * 136 + ks * 32 + lq * 8];
      c2[0][cb] = __builtin_amdgcn_mfma_f32_16x16x32_bf16(a2[0][ks], bf, c2[0][cb], 0, 0, 0);
      c2[1][cb] = __builtin_amdgcn_mfma_f32_16x16x32_bf16(a2[1][ks], bf, c2[1][cb], 0, 0, 0);
    }

  // epilogue: out = x + c2 + b2
#pragma unroll
  for (int cb = 0; cb < 8; ++cb) {
    const int c = cb * 16 + l15;
    const float b2v = b2[c];
#pragma unroll
    for (int t = 0; t < 2; ++t)
#pragma unroll
      for (int r = 0; r < 4; ++r) {
        const int row = rb + t * 16 + lq * 4 + r;
        if (row < N_NODES)
          out[(size_t)row * DIM + c] = x[(size_t)row * DIM + c] + c2[t][cb][r] + b2v;
      }
  }
}

extern "C" void kernel_launch(void* const* d_in, const int* in_sizes, int n_in,
                              void* d_out, int out_size, void* d_ws, size_t ws_size,
                              hipStream_t stream) {
  const float* x     = (const float*)d_in[0];
  const int*   erows = (const int*)d_in[1];
  const int*   ecols = (const int*)d_in[2];
  const float* W1    = (const float*)d_in[3];
  const float* b1    = (const float*)d_in[4];
  const float* W2    = (const float*)d_in[5];
  const float* b2    = (const float*)d_in[6];
  const float* gamma = (const float*)d_in[7];
  const float* beta  = (const float*)d_in[8];
  const float* eps   = (const float*)d_in[9];
  float* out = (float*)d_out;

  char* ws = (char*)d_ws;
  bf16_t* h         = (bf16_t*)(ws);                   // 12,800,000 B
  bf16_t* acc       = (bf16_t*)(ws + 12800000);        // 12,800,000 B
  unsigned int* tmp = (unsigned int*)(ws + 12800000);  // overlays acc (dead until gather)
  int*    sorted    = (int*)(ws + 25600000);           //  3,200,000 B
  int*    starts    = (int*)(ws + 28800000);           //    200,016 B
  int*    bstart    = (int*)(ws + 29000016);           //        800 B
  int*    bcursor   = (int*)(ws + 29000816);           //        800 B
  int*    bhist     = (int*)(ws + 29001616);           //        784 B

  hipMemsetAsync(bhist, 0, NBUCKETS * sizeof(int), stream);
  k_ln    <<<N_NODES / 4, 256, 0, stream>>>(x, gamma, beta, h);
  k_bhist <<<(N_EDGES + BINA_EPB - 1) / BINA_EPB, 256, 0, stream>>>(erows, bhist);
  k_bscan <<<1, 256, 0, stream>>>(bhist, bstart, bcursor, starts);
  k_binA  <<<(N_EDGES + BINA_EPB - 1) / BINA_EPB, 256, 0, stream>>>(erows, ecols, bcursor, tmp);
  k_binB  <<<NBUCKETS, 256, 0, stream>>>(tmp, bstart, starts, sorted);
  k_gather<<<N_NODES / 4, 256, 0, stream>>>((const uint2*)h, starts, sorted, eps, acc);
  k_mlp   <<<(N_NODES + 127) / 128, 256, 0, stream>>>(acc, x, W1, b1, W2, b2, out);
}

// Round 6
// 111.939 us; speedup vs baseline: 12.3875x; 1.0423x over previous
//
#include <hip/hip_runtime.h>
#include <hip/hip_bf16.h>

#define N_NODES 50000
#define DIM 128
#define N_EDGES 800000
#define NBUCKETS 196      // ceil(50000/256) nodes>>8 buckets
#define BINA_EPB 4096     // edges per binning block

typedef __bf16 bf16_t;
typedef bf16_t bf16x2 __attribute__((ext_vector_type(2)));
typedef bf16_t bf16x4 __attribute__((ext_vector_type(4)));
typedef bf16_t bf16x8 __attribute__((ext_vector_type(8)));
typedef float f32x4 __attribute__((ext_vector_type(4)));

__device__ __forceinline__ float bf_lo(unsigned int u) {
  return __uint_as_float(u << 16);
}
__device__ __forceinline__ float bf_hi(unsigned int u) {
  return __uint_as_float(u & 0xffff0000u);
}

// ------- Kernel 1: LayerNorm -> h (bf16); block 0 zeroes bhist ------------
__global__ __launch_bounds__(256) void k_ln(
    const float* __restrict__ x, const float* __restrict__ gamma,
    const float* __restrict__ beta, bf16_t* __restrict__ h,
    int* __restrict__ bhist) {
  if (blockIdx.x == 0 && threadIdx.x < NBUCKETS) bhist[threadIdx.x] = 0;
  const int lane = threadIdx.x & 63;
  const int row  = blockIdx.x * 4 + (threadIdx.x >> 6);
  const float2 v = *(const float2*)(x + (size_t)row * DIM + lane * 2);
  float s  = v.x + v.y;
  float ss = v.x * v.x + v.y * v.y;
#pragma unroll
  for (int d = 1; d < 64; d <<= 1) {
    s  += __shfl_xor(s, d);
    ss += __shfl_xor(ss, d);
  }
  const float mu   = s * (1.0f / 128.0f);
  const float var  = ss * (1.0f / 128.0f) - mu * mu;
  const float rstd = rsqrtf(var + 1e-5f);
  const float2 g = *(const float2*)(gamma + lane * 2);
  const float2 b = *(const float2*)(beta + lane * 2);
  const float h0 = (v.x - mu) * rstd * g.x + b.x;
  const float h1 = (v.y - mu) * rstd * g.y + b.y;
  *(bf16x2*)(h + (size_t)row * DIM + lane * 2) = (bf16x2){(bf16_t)h0, (bf16_t)h1};
}

// ---------------- Kernel 2: bucket histogram (LDS-aggregated) -------------
__global__ __launch_bounds__(256) void k_bhist(
    const int* __restrict__ erows, int* __restrict__ bhist) {
  __shared__ int hist[256];
  const int t = threadIdx.x;
  hist[t] = 0;
  __syncthreads();
  const int base = blockIdx.x * BINA_EPB;
#pragma unroll
  for (int i = 0; i < 16; ++i) {
    const int e = base + i * 256 + t;
    if (e < N_EDGES) atomicAdd(&hist[erows[e] >> 8], 1);
  }
  __syncthreads();
  if (t < NBUCKETS && hist[t] > 0) atomicAdd(&bhist[t], hist[t]);
}

// ---------------- Kernel 3: scan of 196 bucket counts ---------------------
__global__ __launch_bounds__(256) void k_bscan(
    const int* __restrict__ bhist, int* __restrict__ bstart,
    int* __restrict__ bcursor, int* __restrict__ starts) {
  const int t = threadIdx.x, lane = t & 63, w = t >> 6;
  const int val = (t < NBUCKETS) ? bhist[t] : 0;
  int v = val;
#pragma unroll
  for (int d = 1; d < 64; d <<= 1) {
    const int n = __shfl_up(v, d);
    if (lane >= d) v += n;
  }
  __shared__ int wsum[4];
  if (lane == 63) wsum[w] = v;
  __syncthreads();
  int woff = 0;
  for (int k = 0; k < w; ++k) woff += wsum[k];
  const int excl = v + woff - val;
  if (t < NBUCKETS) { bstart[t] = excl; bcursor[t] = excl; }
  if (t == NBUCKETS - 1) bstart[NBUCKETS] = excl + val;
  if (t == 0) starts[N_NODES] = N_EDGES;
}

// ---------------- Kernel 4: coarse bucket binning -------------------------
// LDS histogram over 196 buckets (dst>>8); one global atomic per
// (block,bucket) claims a contiguous range; packed (localdst,col) to tmp.
__global__ __launch_bounds__(256) void k_binA(
    const int* __restrict__ erows, const int* __restrict__ ecols,
    int* __restrict__ bcursor, unsigned int* __restrict__ tmp) {
  __shared__ int hist[256];
  const int t = threadIdx.x;
  const int base = blockIdx.x * BINA_EPB;
  hist[t] = 0;
  __syncthreads();
  int bkt[16];
  unsigned int pk[16];
#pragma unroll
  for (int i = 0; i < 16; ++i) {
    const int e = base + i * 256 + t;
    if (e < N_EDGES) {
      const int d = erows[e];
      const int c = ecols[e];
      bkt[i] = d >> 8;
      pk[i] = ((unsigned int)(d & 255) << 16) | (unsigned int)c;
      atomicAdd(&hist[bkt[i]], 1);
    } else {
      bkt[i] = -1;
    }
  }
  __syncthreads();
  const int cnt = hist[t];
  int g = 0;
  if (t < NBUCKETS && cnt > 0) g = atomicAdd(&bcursor[t], cnt);
  __syncthreads();
  hist[t] = g;  // reuse as local write cursor
  __syncthreads();
#pragma unroll
  for (int i = 0; i < 16; ++i) {
    if (bkt[i] >= 0) {
      const int pos = atomicAdd(&hist[bkt[i]], 1);
      tmp[pos] = pk[i];
    }
  }
}

// ---------------- Kernel 5: within-bucket placement + per-node starts -----
// one block per bucket; computes local node histogram + block scan ->
// per-node starts; then places edges into the bucket's contiguous slice.
__global__ __launch_bounds__(256) void k_binB(
    const unsigned int* __restrict__ tmp, const int* __restrict__ bstart,
    int* __restrict__ starts, int* __restrict__ sorted) {
  __shared__ int cnt[256];
  __shared__ int cur[256];
  __shared__ int wsum[4];
  const int b = blockIdx.x, t = threadIdx.x;
  const int rs = bstart[b], re = bstart[b + 1];
  cnt[t] = 0;
  __syncthreads();
  for (int e = rs + t; e < re; e += 256)
    atomicAdd(&cnt[tmp[e] >> 16], 1);
  __syncthreads();
  const int val = cnt[t];
  const int lane = t & 63, w = t >> 6;
  int v = val;
#pragma unroll
  for (int d = 1; d < 64; d <<= 1) {
    const int n = __shfl_up(v, d);
    if (lane >= d) v += n;
  }
  if (lane == 63) wsum[w] = v;
  __syncthreads();
  int woff = 0;
  for (int k = 0; k < w; ++k) woff += wsum[k];
  const int st = rs + v + woff - val;  // exclusive local scan + bucket base
  const int nidx = b * 256 + t;
  if (nidx < N_NODES) starts[nidx] = st;
  cur[t] = st;
  __syncthreads();
  for (int e = rs + t; e < re; e += 256) {
    const unsigned int pv = tmp[e];
    const int pos = atomicAdd(&cur[pv >> 16], 1);
    sorted[pos] = (int)(pv & 0xffffu);
  }
}

// ---------------- Kernel 6: gather-sum: acc = (1+eps)*h + sum h[src] ------
// one wave per node; half-wave owns the full 128-col row (8B/lane);
// 4 edges per half per iteration -> 8 independent loads in flight.
__global__ __launch_bounds__(256) void k_gather(
    const uint2* __restrict__ h4, const int* __restrict__ starts,
    const int* __restrict__ sorted_src, const float* __restrict__ epsp,
    bf16_t* __restrict__ acc) {
  const int tid  = threadIdx.x;
  const int lane = tid & 63;
  const int half = lane >> 5;
  const int l31  = lane & 31;
  const int node = blockIdx.x * 4 + (tid >> 6);
  const int s = starts[node], e = starts[node + 1];
  f32x4 a0 = {0.f, 0.f, 0.f, 0.f};
  f32x4 a1 = {0.f, 0.f, 0.f, 0.f};
  f32x4 a2 = {0.f, 0.f, 0.f, 0.f};
  f32x4 a3 = {0.f, 0.f, 0.f, 0.f};
  for (int base = s; base < e; base += 64) {
    const int cnt = e - base;
    const int m = cnt < 64 ? cnt : 64;
    const int myidx = (lane < m) ? sorted_src[base + lane] : 0;
    for (int j = 0; j < m; j += 8) {
      const int o0 = j + half;
      const int o1 = j + 2 + half;
      const int o2 = j + 4 + half;
      const int o3 = j + 6 + half;
      const int s0 = __shfl(myidx, o0);
      const int s1 = __shfl(myidx, o1);
      const int s2 = __shfl(myidx, o2);
      const int s3 = __shfl(myidx, o3);
      uint2 v0 = h4[(size_t)s0 * 32 + l31];
      uint2 v1 = h4[(size_t)s1 * 32 + l31];
      uint2 v2 = h4[(size_t)s2 * 32 + l31];
      uint2 v3 = h4[(size_t)s3 * 32 + l31];
      if (o0 >= m) { v0.x = 0u; v0.y = 0u; }
      if (o1 >= m) { v1.x = 0u; v1.y = 0u; }
      if (o2 >= m) { v2.x = 0u; v2.y = 0u; }
      if (o3 >= m) { v3.x = 0u; v3.y = 0u; }
      a0[0] += bf_lo(v0.x); a0[1] += bf_hi(v0.x);
      a0[2] += bf_lo(v0.y); a0[3] += bf_hi(v0.y);
      a1[0] += bf_lo(v1.x); a1[1] += bf_hi(v1.x);
      a1[2] += bf_lo(v1.y); a1[3] += bf_hi(v1.y);
      a2[0] += bf_lo(v2.x); a2[1] += bf_hi(v2.x);
      a2[2] += bf_lo(v2.y); a2[3] += bf_hi(v2.y);
      a3[0] += bf_lo(v3.x); a3[1] += bf_hi(v3.x);
      a3[2] += bf_lo(v3.y); a3[3] += bf_hi(v3.y);
    }
  }
  f32x4 t = (a0 + a1) + (a2 + a3);
#pragma unroll
  for (int k = 0; k < 4; ++k) t[k] += __shfl_xor(t[k], 32);
  if (half == 0) {
    const uint2 hv = h4[(size_t)node * 32 + l31];
    const float epv = 1.0f + epsp[0];
    t[0] += bf_lo(hv.x) * epv; t[1] += bf_hi(hv.x) * epv;
    t[2] += bf_lo(hv.y) * epv; t[3] += bf_hi(hv.y) * epv;
    *(bf16x4*)(acc + (size_t)node * DIM + l31 * 4) =
        (bf16x4){(bf16_t)t[0], (bf16_t)t[1], (bf16_t)t[2], (bf16_t)t[3]};
  }
}

// ---------------- Kernel 7: fused  silu(acc@W1^T+b1)@W2^T + b2 + x --------
__global__ __launch_bounds__(256) void k_mlp(
    const bf16_t* __restrict__ acc, const float* __restrict__ x,
    const float* __restrict__ W1, const float* __restrict__ b1,
    const float* __restrict__ W2, const float* __restrict__ b2,
    float* __restrict__ out) {
  __shared__ __attribute__((aligned(16))) bf16_t lsA[128 * 136]; // W1, then inter
  __shared__ __attribute__((aligned(16))) bf16_t lsB[128 * 136]; // W2

  const int tid  = threadIdx.x;
  const int lane = tid & 63;
  const int w    = tid >> 6;
  const int l15  = lane & 15;
  const int lq   = lane >> 4;

  // stage W1, W2 -> LDS as bf16
#pragma unroll
  for (int i = 0; i < 16; ++i) {
    const int idx = i * 1024 + tid * 4;
    const int r = idx >> 7, c = idx & 127;
    const float4 v1 = *(const float4*)(W1 + idx);
    const float4 v2 = *(const float4*)(W2 + idx);
    *(bf16x4*)&lsA[r * 136 + c] =
        (bf16x4){(bf16_t)v1.x, (bf16_t)v1.y, (bf16_t)v1.z, (bf16_t)v1.w};
    *(bf16x4*)&lsB[r * 136 + c] =
        (bf16x4){(bf16_t)v2.x, (bf16_t)v2.y, (bf16_t)v2.z, (bf16_t)v2.w};
  }

  const int rb = blockIdx.x * 128 + w * 32;

  // A fragments for GEMM1 straight from global (bf16)
  bf16x8 af[2][4];
#pragma unroll
  for (int t = 0; t < 2; ++t)
#pragma unroll
    for (int ks = 0; ks < 4; ++ks) {
      int row = rb + t * 16 + l15;
      row = row < N_NODES ? row : N_NODES - 1;
      af[t][ks] = *(const bf16x8*)(acc + (size_t)row * DIM + ks * 32 + lq * 8);
    }
  __syncthreads();

  // GEMM1: c1 = acc @ W1^T
  f32x4 c1[2][8] = {};
#pragma unroll
  for (int cb = 0; cb < 8; ++cb)
#pragma unroll
    for (int ks = 0; ks < 4; ++ks) {
      const bf16x8 bf = *(const bf16x8*)&lsA[(cb * 16 + l15) * 136 + ks * 32 + lq * 8];
      c1[0][cb] = __builtin_amdgcn_mfma_f32_16x16x32_bf16(af[0][ks], bf, c1[0][cb], 0, 0, 0);
      c1[1][cb] = __builtin_amdgcn_mfma_f32_16x16x32_bf16(af[1][ks], bf, c1[1][cb], 0, 0, 0);
    }
  __syncthreads(); // all waves done reading W1 region

  // bias + SiLU, write intermediate (bf16) into lsA in row-major [128][136]
#pragma unroll
  for (int cb = 0; cb < 8; ++cb) {
    const float b1v = b1[cb * 16 + l15];
#pragma unroll
    for (int t = 0; t < 2; ++t)
#pragma unroll
      for (int r = 0; r < 4; ++r) {
        float v = c1[t][cb][r] + b1v;
        v = v / (1.0f + __expf(-v));
        const int ri = w * 32 + t * 16 + lq * 4 + r;
        lsA[ri * 136 + cb * 16 + l15] = (bf16_t)v;
      }
  }
  __syncthreads();

  // A fragments for GEMM2 from LDS intermediate
  bf16x8 a2[2][4];
#pragma unroll
  for (int t = 0; t < 2; ++t)
#pragma unroll
    for (int ks = 0; ks < 4; ++ks)
      a2[t][ks] = *(const bf16x8*)&lsA[(w * 32 + t * 16 + l15) * 136 + ks * 32 + lq * 8];

  // GEMM2: c2 = inter @ W2^T
  f32x4 c2[2][8] = {};
#pragma unroll
  for (int cb = 0; cb < 8; ++cb)
#pragma unroll
    for (int ks = 0; ks < 4; ++ks) {
      const bf16x8 bf = *(const bf16x8*)&lsB[(cb * 16 + l15) * 136 + ks * 32 + lq * 8];
      c2[0][cb] = __builtin_amdgcn_mfma_f32_16x16x32_bf16(a2[0][ks], bf, c2[0][cb], 0, 0, 0);
      c2[1][cb] = __builtin_amdgcn_mfma_f32_16x16x32_bf16(a2[1][ks], bf, c2[1][cb], 0, 0, 0);
    }

  // epilogue: out = x + c2 + b2
#pragma unroll
  for (int cb = 0; cb < 8; ++cb) {
    const int c = cb * 16 + l15;
    const float b2v = b2[c];
#pragma unroll
    for (int t = 0; t < 2; ++t)
#pragma unroll
      for (int r = 0; r < 4; ++r) {
        const int row = rb + t * 16 + lq * 4 + r;
        if (row < N_NODES)
          out[(size_t)row * DIM + c] = x[(size_t)row * DIM + c] + c2[t][cb][r] + b2v;
      }
  }
}

extern "C" void kernel_launch(void* const* d_in, const int* in_sizes, int n_in,
                              void* d_out, int out_size, void* d_ws, size_t ws_size,
                              hipStream_t stream) {
  const float* x     = (const float*)d_in[0];
  const int*   erows = (const int*)d_in[1];
  const int*   ecols = (const int*)d_in[2];
  const float* W1    = (const float*)d_in[3];
  const float* b1    = (const float*)d_in[4];
  const float* W2    = (const float*)d_in[5];
  const float* b2    = (const float*)d_in[6];
  const float* gamma = (const float*)d_in[7];
  const float* beta  = (const float*)d_in[8];
  const float* eps   = (const float*)d_in[9];
  float* out = (float*)d_out;

  char* ws = (char*)d_ws;
  bf16_t* h         = (bf16_t*)(ws);                   // 12,800,000 B
  bf16_t* acc       = (bf16_t*)(ws + 12800000);        // 12,800,000 B
  unsigned int* tmp = (unsigned int*)(ws + 12800000);  // overlays acc (dead until gather)
  int*    sorted    = (int*)(ws + 25600000);           //  3,200,000 B
  int*    starts    = (int*)(ws + 28800000);           //    200,016 B
  int*    bstart    = (int*)(ws + 29000016);           //        800 B
  int*    bcursor   = (int*)(ws + 29000816);           //        800 B
  int*    bhist     = (int*)(ws + 29001616);           //        784 B

  k_ln    <<<N_NODES / 4, 256, 0, stream>>>(x, gamma, beta, h, bhist);
  k_bhist <<<(N_EDGES + BINA_EPB - 1) / BINA_EPB, 256, 0, stream>>>(erows, bhist);
  k_bscan <<<1, 256, 0, stream>>>(bhist, bstart, bcursor, starts);
  k_binA  <<<(N_EDGES + BINA_EPB - 1) / BINA_EPB, 256, 0, stream>>>(erows, ecols, bcursor, tmp);
  k_binB  <<<NBUCKETS, 256, 0, stream>>>(tmp, bstart, starts, sorted);
  k_gather<<<N_NODES / 4, 256, 0, stream>>>((const uint2*)h, starts, sorted, eps, acc);
  k_mlp   <<<(N_NODES + 127) / 128, 256, 0, stream>>>(acc, x, W1, b1, W2, b2, out);
}